// Round 8
// baseline (130.323 us; speedup 1.0000x reference)
//
#include <hip/hip_runtime.h>
#include <math.h>

#define N 4096
#define D 512
#define MARGIN 0.05f
#define L2_REG 0.02f
#define N_POS 3
#define NCLASS 100
#define MAXC 128          // max members per class (expected ~41 +/- 7)
#define SLOTS 384         // 3*MAXC fixed pair slots per class
#define PREP_BLOCKS (N / 4)

#define BM 128
#define BN 128
#define BK 64
#define NT (N / BM)       // 32 tiles per dim

typedef unsigned short u16;
typedef __attribute__((ext_vector_type(8))) short bf16x8;
typedef __attribute__((ext_vector_type(8))) unsigned short u16x8;
typedef __attribute__((ext_vector_type(4))) float f32x4;

__device__ __forceinline__ u16 f2bf(float f) {
    unsigned u = __builtin_bit_cast(unsigned, f);
    unsigned r = u + 0x7fffu + ((u >> 16) & 1u);   // round-to-nearest-even
    return (u16)(r >> 16);
}

// ---------- kernel 1: [blocks 0..1023] f32->bf16 + row norms + zero-init
//                      [blocks 1024..1123] per-class pair slots ----------
__global__ __launch_bounds__(256)
void prep_build(const float* __restrict__ X, const int* __restrict__ tgt,
                u16* __restrict__ Xb, float* __restrict__ sqn, float* __restrict__ rown,
                float* __restrict__ l_n, int* __restrict__ cls_cnt,
                int2* __restrict__ pairs, float* __restrict__ out) {
    const int t = threadIdx.x;
    if (blockIdx.x < PREP_BLOCKS) {
        int row  = blockIdx.x * 4 + (t >> 6);
        int lane = t & 63;
        const float* xr = X + (size_t)row * D + lane * 8;
        float4 v0 = *reinterpret_cast<const float4*>(xr);
        float4 v1 = *reinterpret_cast<const float4*>(xr + 4);
        u16x8 o;
        o[0] = f2bf(v0.x); o[1] = f2bf(v0.y); o[2] = f2bf(v0.z); o[3] = f2bf(v0.w);
        o[4] = f2bf(v1.x); o[5] = f2bf(v1.y); o[6] = f2bf(v1.z); o[7] = f2bf(v1.w);
        *reinterpret_cast<u16x8*>(Xb + (size_t)row * D + lane * 8) = o;
        float s = v0.x * v0.x + v0.y * v0.y + v0.z * v0.z + v0.w * v0.w
                + v1.x * v1.x + v1.y * v1.y + v1.z * v1.z + v1.w * v1.w;
        #pragma unroll
        for (int off = 32; off; off >>= 1) s += __shfl_xor(s, off);
        if (lane == 0) {
            sqn[row]  = s;
            rown[row] = sqrtf(s);
        }
        // zero-init accumulators (ws/out poisoned 0xAA before every call)
        if (t < 4) l_n[blockIdx.x * 4 + t] = 0.f;
        if (blockIdx.x == 0 && t == 0) out[0] = 0.f;
        return;
    }

    // ---- build path: one block per class ----
    const int c = blockIdx.x - PREP_BLOCKS;
    __shared__ int idxs[MAXC];
    __shared__ int cnt;
    __shared__ int woff[4], wbase[4];
    if (t == 0) cnt = 0;
    __syncthreads();

    for (int j0 = 0; j0 < N; j0 += 256) {
        int j = j0 + t;
        bool m = (tgt[j] == c);
        unsigned long long bal = __ballot(m);
        if ((t & 63) == 0) woff[t >> 6] = __popcll(bal);
        __syncthreads();
        if (t == 0) {
            int s = cnt;
            #pragma unroll
            for (int w = 0; w < 4; ++w) { wbase[w] = s; s += woff[w]; }
            cnt = s;
        }
        __syncthreads();
        if (m) {
            int lane = t & 63;
            int pos = wbase[t >> 6] + __popcll(bal & ((1ull << lane) - 1ull));
            if (pos < MAXC) idxs[pos] = j;
        }
        __syncthreads();
    }

    const int n  = cnt < MAXC ? cnt : MAXC;
    const int n1 = n - 1 > 0 ? n - 1 : 0;
    const int n2 = n - 2 > 0 ? n - 2 : 0;
    const int n3 = n - 3 > 0 ? n - 3 : 0;
    if (t == 0) cls_cnt[c] = n1 + n2 + n3;
    int2* reg = pairs + c * SLOTS;
    for (int s = t; s < SLOTS; s += 256) {
        int2 v = make_int2(-1, -1);
        if (s < n1)                v = make_int2(idxs[s], idxs[s + 1]);
        else if (s < n1 + n2)      { int p = s - n1;      v = make_int2(idxs[p], idxs[p + 2]); }
        else if (s < n1 + n2 + n3) { int p = s - n1 - n2; v = make_int2(idxs[p], idxs[p + 3]); }
        reg[s] = v;   // each slot written exactly once -> no barrier needed
    }
}

// ---------- kernel 2: triangular MFMA X.X^T + fused dist/exp/mask, row+col reduce ----------
// LDS: single-buffered linear row-major [128][64] bf16 per tile, XOR-swizzled 16B octets:
//   phys(row, Q) = row*64 + (Q ^ (row&7))*8   (elements)
// Swizzle pre-applied to the per-lane GLOBAL source address (rule #21):
// linear LDS dest + inverse-swz source + swz on ds_read.
// Single buffer = 32 KB LDS -> 4 blocks/CU (vs 2 with dbuf); m97/m99 showed
// explicit dbuf buys nothing at the barrier (vmcnt(0) drain), occupancy wins.
__global__ __launch_bounds__(256, 4)
void lneg_mfma(const u16* __restrict__ Xb, const int* __restrict__ tgt,
               const float* __restrict__ sqn, float* __restrict__ l_n) {
    // triangular tile index: z -> (bi, bj), bi <= bj
    int z = blockIdx.x;
    int bi = (int)((2 * NT + 1 - sqrtf((float)((2 * NT + 1) * (2 * NT + 1)) - 8.0f * (float)z)) * 0.5f);
    while (z <  bi * (2 * NT + 1 - bi) / 2) --bi;
    while (z >= (bi + 1) * (2 * NT - bi) / 2) ++bi;
    const int bj = bi + (z - bi * (2 * NT + 1 - bi) / 2);
    const int row0 = bi * BM, col0 = bj * BN;
    const bool offdiag = (bi != bj);

    __shared__ u16 As[BM * BK];   // 16 KB
    __shared__ u16 Bs[BN * BK];   // 16 KB
    const int t = threadIdx.x;
    const int w = t >> 6, l = t & 63;
    const int wr = w >> 1, wc = w & 1;       // wave quadrant: 64x64 output
    const int lc = l & 15, lg = l >> 4;
    const int swz = lc & 7;

    f32x4 acc[4][4] = {};

    for (int kt = 0; kt < D / BK; ++kt) {
        const int kk = kt * BK;
        // stage: phys chunk pc = w*256+q*64+l; r = pc>>3, vq = pc&7, logical octet = vq^(r&7)
        #pragma unroll
        for (int q = 0; q < 4; ++q) {
            int pc = w * 256 + q * 64 + l;
            int r = pc >> 3, vq = pc & 7;
            int ql = vq ^ (r & 7);
            const u16* ga = Xb + (size_t)(row0 + r) * D + kk + ql * 8;
            const u16* gb = Xb + (size_t)(col0 + r) * D + kk + ql * 8;
            u16* la = &As[(w * 256 + q * 64) * 8];   // wave-uniform base; HW adds lane*16
            u16* lb = &Bs[(w * 256 + q * 64) * 8];
            __builtin_amdgcn_global_load_lds((const __attribute__((address_space(1))) unsigned int*)ga,
                                             (__attribute__((address_space(3))) unsigned int*)la, 16, 0, 0);
            __builtin_amdgcn_global_load_lds((const __attribute__((address_space(1))) unsigned int*)gb,
                                             (__attribute__((address_space(3))) unsigned int*)lb, 16, 0, 0);
        }
        __syncthreads();   // drains vmcnt before ds_read

        bf16x8 af[4][2], bfr[4][2];
        #pragma unroll
        for (int fm = 0; fm < 4; ++fm)
            #pragma unroll
            for (int ks = 0; ks < 2; ++ks) {
                int row = wr * 64 + fm * 16 + lc;
                int Q   = ks * 4 + lg;
                af[fm][ks] = *reinterpret_cast<const bf16x8*>(&As[row * 64 + ((Q ^ swz) * 8)]);
            }
        #pragma unroll
        for (int fn = 0; fn < 4; ++fn)
            #pragma unroll
            for (int ks = 0; ks < 2; ++ks) {
                int col = wc * 64 + fn * 16 + lc;
                int Q   = ks * 4 + lg;
                bfr[fn][ks] = *reinterpret_cast<const bf16x8*>(&Bs[col * 64 + ((Q ^ swz) * 8)]);
            }
        #pragma unroll
        for (int fm = 0; fm < 4; ++fm)
            #pragma unroll
            for (int fn = 0; fn < 4; ++fn) {
                acc[fm][fn] = __builtin_amdgcn_mfma_f32_16x16x32_bf16(af[fm][0], bfr[fn][0], acc[fm][fn], 0, 0, 0);
                acc[fm][fn] = __builtin_amdgcn_mfma_f32_16x16x32_bf16(af[fm][1], bfr[fn][1], acc[fm][fn], 0, 0, 0);
            }
        __syncthreads();   // protect LDS before next stage
    }

    // epilogue: C layout col = l&15, row = (l>>4)*4 + reg  [guide m89]
    int tgj[4]; float sqj[4];
    #pragma unroll
    for (int fn = 0; fn < 4; ++fn) {
        int gj = col0 + wc * 64 + fn * 16 + lc;
        tgj[fn] = tgt[gj]; sqj[fn] = sqn[gj];
    }
    float csum[4] = {};
    #pragma unroll
    for (int fm = 0; fm < 4; ++fm) {
        #pragma unroll
        for (int r = 0; r < 4; ++r) {
            int gi = row0 + wr * 64 + fm * 16 + lg * 4 + r;
            float sqi = sqn[gi]; int tgi = tgt[gi];
            float rs = 0.f;
            #pragma unroll
            for (int fn = 0; fn < 4; ++fn) {
                float sq = sqi + sqj[fn] - 2.f * acc[fm][fn][r];
                sq = fmaxf(sq, 0.f);
                float dd = sq > 1e-12f ? sqrtf(sq) : 0.f;
                float e = (tgi != tgj[fn]) ? __expf(MARGIN - dd) : 0.f;
                rs += e;
                csum[fn] += e;
            }
            rs += __shfl_xor(rs, 1); rs += __shfl_xor(rs, 2);
            rs += __shfl_xor(rs, 4); rs += __shfl_xor(rs, 8);
            if (lc == 0) atomicAdd(&l_n[gi], rs);
        }
    }
    if (offdiag) {
        #pragma unroll
        for (int fn = 0; fn < 4; ++fn) {
            float s = csum[fn];
            s += __shfl_xor(s, 16); s += __shfl_xor(s, 32);
            if (lg == 0) atomicAdd(&l_n[col0 + wc * 64 + fn * 16 + lc], s);
        }
    }
}

// ---------- kernel 3: grid-stride pair loss over sentinel slots + fused finalize ----------
#define PL_BLOCKS 256
__global__ __launch_bounds__(256)
void pair_loss(const float* __restrict__ X, const float* __restrict__ sqn,
               const float* __restrict__ rown, const float* __restrict__ l_n,
               const int2* __restrict__ pairs, const int* __restrict__ cls_cnt,
               float* __restrict__ out) {
    const int t = threadIdx.x;
    const int lane = t & 63;
    const int wid0 = blockIdx.x * 4 + (t >> 6);
    float local = 0.f;
    for (int p = wid0; p < NCLASS * SLOTS; p += PL_BLOCKS * 4) {
        int2 pr = pairs[p];
        if (pr.x < 0) continue;     // sentinel slot (uniform across wave)
        const float* xi = X + (size_t)pr.x * D + lane * 8;
        const float* xj = X + (size_t)pr.y * D + lane * 8;
        float4 a0 = *reinterpret_cast<const float4*>(xi);
        float4 a1 = *reinterpret_cast<const float4*>(xi + 4);
        float4 b0 = *reinterpret_cast<const float4*>(xj);
        float4 b1 = *reinterpret_cast<const float4*>(xj + 4);
        float s = a0.x * b0.x + a0.y * b0.y + a0.z * b0.z + a0.w * b0.w
                + a1.x * b1.x + a1.y * b1.y + a1.z * b1.z + a1.w * b1.w;
        #pragma unroll
        for (int off = 32; off; off >>= 1) s += __shfl_xor(s, off);
        if (lane == 0) {
            float sq = sqn[pr.x] + sqn[pr.y] - 2.f * s;
            sq = fmaxf(sq, 0.f);
            float dd = sq > 1e-12f ? sqrtf(sq) : 0.f;
            float ln = logf(l_n[pr.x] + l_n[pr.y]);
            float pl = fmaxf(ln + dd, 0.f);
            local += pl * pl;
        }
    }
    __shared__ float wsum[4];
    if (lane == 0) wsum[t >> 6] = local;
    __syncthreads();
    if (t == 0) {
        int np = 0;
        #pragma unroll
        for (int c = 0; c < NCLASS; ++c) np += cls_cnt[c];
        if (np > 0)
            atomicAdd(out, (wsum[0] + wsum[1] + wsum[2] + wsum[3]) / (float)np);
    }

    // block 0 also folds in the L2 term
    if (blockIdx.x == 0) {
        float s = 0.f;
        for (int i = t; i < N; i += 256) s += rown[i];
        #pragma unroll
        for (int off = 32; off; off >>= 1) s += __shfl_xor(s, off);
        __shared__ float nsum[4];
        if (lane == 0) nsum[t >> 6] = s;
        __syncthreads();
        if (t == 0)
            atomicAdd(out, L2_REG * (nsum[0] + nsum[1] + nsum[2] + nsum[3]) / (float)N);
    }
}

extern "C" void kernel_launch(void* const* d_in, const int* in_sizes, int n_in,
                              void* d_out, int out_size, void* d_ws, size_t ws_size,
                              hipStream_t stream) {
    const float* X   = (const float*)d_in[0];
    const int*   tgt = (const int*)d_in[1];

    u16*   Xb = (u16*)d_ws;                                   // N*D bf16 = 4 MB
    float* fw = (float*)((char*)d_ws + (size_t)N * D * 2);
    float* sqn     = fw;                // N
    float* rown    = fw + N;            // N
    float* l_n     = fw + 2 * N;        // N
    int*   cls_cnt = (int*)(fw + 3 * N);                      // NCLASS (pad to 128)
    int2*  pairs   = (int2*)(fw + 3 * N + 128);               // NCLASS*SLOTS int2

    prep_build<<<PREP_BLOCKS + NCLASS, 256, 0, stream>>>(X, tgt, Xb, sqn, rown, l_n,
                                                         cls_cnt, pairs, (float*)d_out);
    lneg_mfma<<<NT * (NT + 1) / 2, 256, 0, stream>>>(Xb, tgt, sqn, l_n);
    pair_loss<<<PL_BLOCKS, 256, 0, stream>>>(X, sqn, rown, l_n, pairs, cls_cnt, (float*)d_out);
}